// Round 12
// baseline (378.563 us; speedup 1.0000x reference)
//
#include <hip/hip_runtime.h>
#include <hip/hip_bf16.h>
#include <hip/hip_fp16.h>

// ---------------------------------------------------------------------------
// 2-layer GAT (PyG GATConv semantics).
// Round 12 = round 11 (264 us) + two isolated deltas:
//  (1) GEMM row tile 64 -> 32 (1250 blocks, ~2.4 waves/SIMD vs 1.2): same
//      work, 2x the wave-level latency hiding for staging + barriers.
//  (2) output head fused into agg2: init_out writes (b2@Wout + bout), each
//      (node,head) block atomically adds 0.25*v@Wout. final_fused kernel and
//      agg2's 20.5 MB write + re-read are deleted.
// Aggregate inner loop byte-for-byte r11 (ELL gather, fma_mix, 48 us).
// ---------------------------------------------------------------------------

#define HEADS 4
#define CDIM 64
#define HC 256   // HEADS*CDIM
#define ELLW 96  // ELL row stride (ints)

typedef __attribute__((ext_vector_type(8))) short bf16x8;   // 8 bf16 = 4 VGPR
typedef __attribute__((ext_vector_type(4))) float f32x4;    // MFMA acc

__device__ __forceinline__ short f32_to_bf16_rne(float v) {
  unsigned u = __float_as_uint(v);
  unsigned r = (u + 0x7FFFu + ((u >> 16) & 1u)) >> 16;
  return (short)r;
}
__device__ __forceinline__ float bf16_bits_to_f32(short s) {
  return __uint_as_float(((unsigned)(unsigned short)s) << 16);
}

// acc_lo += f16lo(reg)*ex ; acc_hi += f16hi(reg)*ex   (f32 accumulate)
__device__ __forceinline__ void fma_mix2(float& alo, float& ahi,
                                         unsigned reg, float ex) {
  asm("v_fma_mix_f32 %0, %2, %3, %0 op_sel:[0,0,0] op_sel_hi:[1,0,0]\n\t"
      "v_fma_mix_f32 %1, %2, %3, %1 op_sel:[1,0,0] op_sel_hi:[1,0,0]"
      : "+v"(alo), "+v"(ahi)
      : "v"(reg), "v"(ex));
}
__device__ __forceinline__ void fma_mix8(float ex, const uint4& u, float* acc) {
  fma_mix2(acc[0], acc[1], u.x, ex);
  fma_mix2(acc[2], acc[3], u.y, ex);
  fma_mix2(acc[4], acc[5], u.z, ex);
  fma_mix2(acc[6], acc[7], u.w, ex);
}

// -------- weight pack (W1+W2 one launch): W[K][256] -> Wt_hi/lo [256][K] ---
__global__ __launch_bounds__(256) void pack_w12_kernel(
    const float* __restrict__ W1, short* __restrict__ W1h,
    short* __restrict__ W1l, const float* __restrict__ W2,
    short* __restrict__ W2h, short* __restrict__ W2l) {
  const int i = blockIdx.x * 256 + threadIdx.x;
  if (i < 128 * 256) {
    const int k = i >> 8, n = i & 255;
    const float v = W1[i];
    const short hi = f32_to_bf16_rne(v);
    W1h[n * 128 + k] = hi;
    W1l[n * 128 + k] = f32_to_bf16_rne(v - bf16_bits_to_f32(hi));
  } else {
    const int j = i - 128 * 256;
    if (j >= 256 * 256) return;
    const int k = j >> 8, n = j & 255;
    const float v = W2[j];
    const short hi = f32_to_bf16_rne(v);
    W2h[n * 256 + k] = hi;
    W2l[n * 256 + k] = f32_to_bf16_rne(v - bf16_bits_to_f32(hi));
  }
}

// -------- init d_out with the constant term: (b2 @ Wout + bout)[j] ---------
__global__ __launch_bounds__(256) void init_out_kernel(
    const float* __restrict__ b2, const float* __restrict__ Wout,
    const float* __restrict__ bout, float* __restrict__ out, int total) {
  const int i = blockIdx.x * 256 + threadIdx.x;
  if (i >= total) return;
  const int j = i & 15;
  float s = bout[j];
#pragma unroll
  for (int k = 0; k < CDIM; ++k) s += b2[k] * Wout[k * 16 + j];
  out[i] = s;
}

// ---------------- split-bf16 MFMA GEMM: h = A[M,K] @ W[K,256] --------------
// Row tile 32 (M=20000 = 625*32): block = 128 thr (2 waves); wave w covers
// cols col0 = by*128 + w*64 (one head). A staged f32 -> hi/lo bf16 via LDS;
// B frags direct from global (L2-resident). 24 MFMA/wave/k-step.
// Epilogue: f16 h write + fused a_s/a_d scores (quad shfl reduction).
__global__ __launch_bounds__(128) void gemm_mfma_split(
    const float* __restrict__ A, const short* __restrict__ Wt_hi,
    const short* __restrict__ Wt_lo, __half* __restrict__ h16,
    const float* __restrict__ att_s, const float* __restrict__ att_d,
    float* __restrict__ a_s, float* __restrict__ a_d, int M, int K) {
  __shared__ alignas(16) short As_hi[32 * 32];
  __shared__ alignas(16) short As_lo[32 * 32];
  const int t = threadIdx.x;
  const int wave = t >> 6;
  const int lane = t & 63;
  const int quad = lane >> 4;
  const int m16 = lane & 15;
  const int row0 = blockIdx.x * 32;
  const int col0 = blockIdx.y * 128 + wave * 64;   // == head*64
  const int head = col0 >> 6;

  f32x4 acc[2][4] = {};  // [mt][nt]

  for (int k0 = 0; k0 < K; k0 += 32) {
    if (k0) __syncthreads();
    // ---- stage A tile 32 rows x 32 k as hi/lo bf16 (1 unit per thread) ----
    {
      const int r = t >> 2, seg = t & 3;
      const int gr = row0 + r;
      float vv[8] = {0.f, 0.f, 0.f, 0.f, 0.f, 0.f, 0.f, 0.f};
      if (gr < M) {
        const float* ap = A + (size_t)gr * K + k0 + seg * 8;
        const float4 v0 = *(const float4*)ap;
        const float4 v1 = *(const float4*)(ap + 4);
        vv[0] = v0.x; vv[1] = v0.y; vv[2] = v0.z; vv[3] = v0.w;
        vv[4] = v1.x; vv[5] = v1.y; vv[6] = v1.z; vv[7] = v1.w;
      }
      bf16x8 h8, l8;
#pragma unroll
      for (int j = 0; j < 8; ++j) {
        const short hi = f32_to_bf16_rne(vv[j]);
        h8[j] = hi;
        l8[j] = f32_to_bf16_rne(vv[j] - bf16_bits_to_f32(hi));
      }
      *(bf16x8*)(As_hi + r * 32 + seg * 8) = h8;
      *(bf16x8*)(As_lo + r * 32 + seg * 8) = l8;
    }
    bf16x8 b_hi[4], b_lo[4];
#pragma unroll
    for (int nt = 0; nt < 4; ++nt) {
      const size_t off = (size_t)(col0 + nt * 16 + m16) * K + k0 + quad * 8;
      b_hi[nt] = *(const bf16x8*)(Wt_hi + off);
      b_lo[nt] = *(const bf16x8*)(Wt_lo + off);
    }
    __syncthreads();
    bf16x8 a_hi[2], a_lo[2];
#pragma unroll
    for (int mt = 0; mt < 2; ++mt) {
      const int off = (mt * 16 + m16) * 32 + quad * 8;
      a_hi[mt] = *(const bf16x8*)(As_hi + off);
      a_lo[mt] = *(const bf16x8*)(As_lo + off);
    }
#pragma unroll
    for (int mt = 0; mt < 2; ++mt)
#pragma unroll
      for (int nt = 0; nt < 4; ++nt) {
        acc[mt][nt] = __builtin_amdgcn_mfma_f32_16x16x32_bf16(
            a_hi[mt], b_hi[nt], acc[mt][nt], 0, 0, 0);
        acc[mt][nt] = __builtin_amdgcn_mfma_f32_16x16x32_bf16(
            a_hi[mt], b_lo[nt], acc[mt][nt], 0, 0, 0);
        acc[mt][nt] = __builtin_amdgcn_mfma_f32_16x16x32_bf16(
            a_lo[mt], b_hi[nt], acc[mt][nt], 0, 0, 0);
      }
  }
  float sa[4], da[4];
#pragma unroll
  for (int nt = 0; nt < 4; ++nt) {
    sa[nt] = att_s[col0 + nt * 16 + m16];
    da[nt] = att_d[col0 + nt * 16 + m16];
  }
#pragma unroll
  for (int mt = 0; mt < 2; ++mt)
#pragma unroll
    for (int r = 0; r < 4; ++r) {
      const int gr = row0 + mt * 16 + quad * 4 + r;
      float ps = acc[mt][0][r] * sa[0] + acc[mt][1][r] * sa[1] +
                 acc[mt][2][r] * sa[2] + acc[mt][3][r] * sa[3];
      float pd = acc[mt][0][r] * da[0] + acc[mt][1][r] * da[1] +
                 acc[mt][2][r] * da[2] + acc[mt][3][r] * da[3];
#pragma unroll
      for (int off = 1; off <= 8; off <<= 1) {
        ps += __shfl_xor(ps, off);
        pd += __shfl_xor(pd, off);
      }
      if (gr < M) {
        if (m16 == 0) {
          a_s[gr * HEADS + head] = ps;
          a_d[gr * HEADS + head] = pd;
        }
#pragma unroll
        for (int nt = 0; nt < 4; ++nt)
          h16[(size_t)gr * HC + col0 + nt * 16 + m16] =
              __float2half(acc[mt][nt][r]);
      }
    }
}

// ============ ELL build: one kernel, no histogram/scan needed ==============
__global__ __launch_bounds__(256) void ell_scatter_kernel(
    const int* __restrict__ src, const int* __restrict__ dst,
    int* __restrict__ cnt, int* __restrict__ ell, int E_raw, int Etot) {
  const int e = blockIdx.x * 256 + threadIdx.x;
  if (e >= Etot) return;
  const int s = (e < E_raw) ? src[e] : (e - E_raw);
  const int d = (e < E_raw) ? dst[e] : (e - E_raw);
  const int pos = atomicAdd(&cnt[d], 1);
  if (pos < ELLW) ell[d * ELLW + pos] = s;  // P(overflow) ~ 7e-18
}

// ================= fused softmax + aggregation (f16 gather) ================
// grid = N blocks. block b: head hd = b&3 (XCD-affine), nodes 4*(b>>2)..+3
// (wave = node). lane: q = lane>>3 edge slot (stride 8, pair-unrolled),
// oc = lane&7 channel octet (8 f16 ch = one 16B load). fma_mix inner math.
// mode 0: out[n,c] = ELU(v + b[c])  (layer-1 output, [N,256])
// mode 1: d_out[n,:] += 0.25 * v @ Wout  (fused output head, atomicAdd)
__global__ __launch_bounds__(256) void gat_aggregate_kernel(
    const int* __restrict__ cnt, const int* __restrict__ ell,
    const __half* __restrict__ h16, const float* __restrict__ a_s,
    const float* __restrict__ a_d, const float* __restrict__ b,
    const float* __restrict__ Wout, float* __restrict__ out, int mode) {
  const int bid = blockIdx.x;
  const int hd = bid & 3;
  const int n = (bid >> 2) * 4 + (threadIdx.x >> 6);
  const int lane = threadIdx.x & 63;
  const int q = lane >> 3;
  const int oc = lane & 7;
  const float ad = a_d[n * HEADS + hd];
  const int deg = cnt[n];
  const int* __restrict__ row = ell + n * ELLW;
  const char* hbase = (const char*)h16 + hd * 128 + oc * 16;  // bytes
  const float* asb = a_s + hd;
  float acc[8] = {0.f, 0.f, 0.f, 0.f, 0.f, 0.f, 0.f, 0.f};
  float den = 0.f;
  int i = q;
  for (; i + 8 < deg; i += 16) {
    const int s0 = row[i];
    const int s1 = row[i + 8];
    const float as0 = asb[s0 * 4];
    const float as1 = asb[s1 * 4];
    const uint4 u0 = *(const uint4*)(hbase + ((unsigned)s0 << 9));
    const uint4 u1 = *(const uint4*)(hbase + ((unsigned)s1 << 9));
    float a0 = as0 + ad; a0 = fmaxf(a0, 0.2f * a0);
    float a1 = as1 + ad; a1 = fmaxf(a1, 0.2f * a1);
    const float e0 = __expf(a0);
    const float e1 = __expf(a1);
    den += e0 + e1;
    fma_mix8(e0, u0, acc);
    fma_mix8(e1, u1, acc);
  }
  for (; i < deg; i += 8) {
    const int s = row[i];
    float a = asb[s * 4] + ad;
    a = fmaxf(a, 0.2f * a);
    const float ex = __expf(a);
    den += ex;
    const uint4 u = *(const uint4*)(hbase + ((unsigned)s << 9));
    fma_mix8(ex, u, acc);
  }
  // reduce across the 8 slots (lane bits 3,4,5)
#pragma unroll
  for (int off = 8; off <= 32; off <<= 1) {
#pragma unroll
    for (int k = 0; k < 8; ++k) acc[k] += __shfl_xor(acc[k], off);
    den += __shfl_xor(den, off);
  }
  if (lane < 8) {
    const float inv = 1.f / den;
    float u[8];
#pragma unroll
    for (int k = 0; k < 8; ++k) u[k] = acc[k] * inv;
    if (mode == 0) {
      const float* bb = b + hd * CDIM + oc * 8;
#pragma unroll
      for (int k = 0; k < 8; ++k) {
        const float t0 = u[k] + bb[k];
        u[k] = (t0 > 0.f) ? t0 : (__expf(t0) - 1.f);
      }
      float* op = out + (size_t)n * HC + hd * CDIM + oc * 8;
      *(float4*)op = make_float4(u[0], u[1], u[2], u[3]);
      *(float4*)(op + 4) = make_float4(u[4], u[5], u[6], u[7]);
    } else {
      // fused output head: this head's contribution 0.25 * v @ Wout
      float p[16];
#pragma unroll
      for (int j = 0; j < 16; ++j) p[j] = 0.f;
#pragma unroll
      for (int k = 0; k < 8; ++k) {
        const float m = 0.25f * u[k];
        const float4* wr = (const float4*)(Wout + (oc * 8 + k) * 16);
        const float4 w0 = wr[0], w1 = wr[1], w2 = wr[2], w3 = wr[3];
        p[0] += m * w0.x;  p[1] += m * w0.y;
        p[2] += m * w0.z;  p[3] += m * w0.w;
        p[4] += m * w1.x;  p[5] += m * w1.y;
        p[6] += m * w1.z;  p[7] += m * w1.w;
        p[8] += m * w2.x;  p[9] += m * w2.y;
        p[10] += m * w2.z; p[11] += m * w2.w;
        p[12] += m * w3.x; p[13] += m * w3.y;
        p[14] += m * w3.z; p[15] += m * w3.w;
      }
      // reduce across the 8 octet lanes (xor 1,2,4 stays within lanes 0..7)
#pragma unroll
      for (int off = 1; off <= 4; off <<= 1)
#pragma unroll
        for (int j = 0; j < 16; ++j) p[j] += __shfl_xor(p[j], off);
      if (oc == 0) {
        float* op = out + (size_t)n * 16;
#pragma unroll
        for (int j = 0; j < 16; ++j) atomicAdd(op + j, p[j]);
      }
    }
  }
}

extern "C" void kernel_launch(void* const* d_in, const int* in_sizes, int n_in,
                              void* d_out, int out_size, void* d_ws, size_t ws_size,
                              hipStream_t stream) {
  const float* x      = (const float*)d_in[0];
  const int*   eidx   = (const int*)d_in[1];
  const float* W1     = (const float*)d_in[2];
  const float* att_s1 = (const float*)d_in[3];
  const float* att_d1 = (const float*)d_in[4];
  const float* b1     = (const float*)d_in[5];
  const float* W2     = (const float*)d_in[6];
  const float* att_s2 = (const float*)d_in[7];
  const float* att_d2 = (const float*)d_in[8];
  const float* b2     = (const float*)d_in[9];
  const float* Wout   = (const float*)d_in[10];
  const float* bout   = (const float*)d_in[11];
  float* out          = (float*)d_out;

  const int N     = in_sizes[0] / 128;   // 20000
  const int E_raw = in_sizes[1] / 2;     // 640000
  const int Etot  = E_raw + N;           // + self loops
  const int* src = eidx;
  const int* dst = eidx + E_raw;

  // ---- workspace layout ----
  float* ws = (float*)d_ws;
  float* buf_agg = ws;                          // [N,256] layer-1 ELU output
  float* buf_as  = buf_agg + (size_t)N * HC;    // [N,4]
  float* buf_ad  = buf_as + (size_t)N * HEADS;  // [N,4]
  __half* h16    = (__half*)(buf_ad + (size_t)N * HEADS);  // [N,256] f16
  int* cnt  = (int*)(h16 + (size_t)N * HC);     // [N] degree counters
  int* ell  = cnt + N;                          // [N*ELLW]
  uintptr_t wp = ((uintptr_t)(ell + (size_t)N * ELLW) + 15) & ~(uintptr_t)15;
  short* wt1_hi = (short*)wp;                   // [256][128]
  short* wt1_lo = wt1_hi + 256 * 128;
  short* wt2_hi = wt1_lo + 256 * 128;           // [256][256]
  short* wt2_lo = wt2_hi + 256 * 256;

  const dim3 blk(256);
  const int g_edge = (Etot + 255) / 256;
  const dim3 g_gemm((N + 31) / 32, 2);          // 625 x 2 blocks
  const dim3 blk_gemm(128);

  // ================= weight pack + ELL build + out init =================
  pack_w12_kernel<<<(384 * 256 + 255) / 256, blk, 0, stream>>>(
      W1, wt1_hi, wt1_lo, W2, wt2_hi, wt2_lo);
  hipMemsetAsync(cnt, 0, (size_t)N * sizeof(int), stream);
  ell_scatter_kernel<<<g_edge, blk, 0, stream>>>(src, dst, cnt, ell, E_raw, Etot);
  init_out_kernel<<<(N * 16 + 255) / 256, blk, 0, stream>>>(b2, Wout, bout,
                                                            out, N * 16);

  // ================= Layer 1 =================
  gemm_mfma_split<<<g_gemm, blk_gemm, 0, stream>>>(
      x, wt1_hi, wt1_lo, h16, att_s1, att_d1, buf_as, buf_ad, N, 128);
  gat_aggregate_kernel<<<N, blk, 0, stream>>>(cnt, ell, h16, buf_as,
                                              buf_ad, b1, Wout, buf_agg, 0);

  // ================= Layer 2 (output head fused into aggregate) ============
  gemm_mfma_split<<<g_gemm, blk_gemm, 0, stream>>>(
      buf_agg, wt2_hi, wt2_lo, h16, att_s2, att_d2, buf_as, buf_ad, N, 256);
  gat_aggregate_kernel<<<N, blk, 0, stream>>>(cnt, ell, h16, buf_as,
                                              buf_ad, b2, Wout, out, 1);
}

// Round 13
// 264.533 us; speedup vs baseline: 1.4311x; 1.4311x over previous
//
#include <hip/hip_runtime.h>
#include <hip/hip_bf16.h>
#include <hip/hip_fp16.h>

// ---------------------------------------------------------------------------
// 2-layer GAT (PyG GATConv semantics).
// Round 13 = round 11 (best, 264 us) with ONE isolated delta:
//   GEMM row tile 64 -> 32 (1250 blocks => ~2.4 waves/SIMD vs 1.2): same
//   total work, 2x wave-level overlap of staging/barrier with MFMA.
// r12's in-aggregate output-head fusion REVERTED (it spilled: VGPR 20->40,
// WRITE 20->40 MB scratch, agg 48->160 us). Aggregate, ELL build, final head
// are byte-for-byte r11.
// ---------------------------------------------------------------------------

#define HEADS 4
#define CDIM 64
#define HC 256   // HEADS*CDIM
#define ELLW 96  // ELL row stride (ints)

typedef __attribute__((ext_vector_type(8))) short bf16x8;   // 8 bf16 = 4 VGPR
typedef __attribute__((ext_vector_type(4))) float f32x4;    // MFMA acc

__device__ __forceinline__ short f32_to_bf16_rne(float v) {
  unsigned u = __float_as_uint(v);
  unsigned r = (u + 0x7FFFu + ((u >> 16) & 1u)) >> 16;
  return (short)r;
}
__device__ __forceinline__ float bf16_bits_to_f32(short s) {
  return __uint_as_float(((unsigned)(unsigned short)s) << 16);
}

// acc_lo += f16lo(reg)*ex ; acc_hi += f16hi(reg)*ex   (f32 accumulate)
__device__ __forceinline__ void fma_mix2(float& alo, float& ahi,
                                         unsigned reg, float ex) {
  asm("v_fma_mix_f32 %0, %2, %3, %0 op_sel:[0,0,0] op_sel_hi:[1,0,0]\n\t"
      "v_fma_mix_f32 %1, %2, %3, %1 op_sel:[1,0,0] op_sel_hi:[1,0,0]"
      : "+v"(alo), "+v"(ahi)
      : "v"(reg), "v"(ex));
}
__device__ __forceinline__ void fma_mix8(float ex, const uint4& u, float* acc) {
  fma_mix2(acc[0], acc[1], u.x, ex);
  fma_mix2(acc[2], acc[3], u.y, ex);
  fma_mix2(acc[4], acc[5], u.z, ex);
  fma_mix2(acc[6], acc[7], u.w, ex);
}

// -------- weight pack (W1+W2 one launch): W[K][256] -> Wt_hi/lo [256][K] ---
__global__ __launch_bounds__(256) void pack_w12_kernel(
    const float* __restrict__ W1, short* __restrict__ W1h,
    short* __restrict__ W1l, const float* __restrict__ W2,
    short* __restrict__ W2h, short* __restrict__ W2l) {
  const int i = blockIdx.x * 256 + threadIdx.x;
  if (i < 128 * 256) {
    const int k = i >> 8, n = i & 255;
    const float v = W1[i];
    const short hi = f32_to_bf16_rne(v);
    W1h[n * 128 + k] = hi;
    W1l[n * 128 + k] = f32_to_bf16_rne(v - bf16_bits_to_f32(hi));
  } else {
    const int j = i - 128 * 256;
    if (j >= 256 * 256) return;
    const int k = j >> 8, n = j & 255;
    const float v = W2[j];
    const short hi = f32_to_bf16_rne(v);
    W2h[n * 256 + k] = hi;
    W2l[n * 256 + k] = f32_to_bf16_rne(v - bf16_bits_to_f32(hi));
  }
}

// ---------------- split-bf16 MFMA GEMM: h = A[M,K] @ W[K,256] --------------
// Row tile 32 (M=20000 = 625*32): block = 128 thr (2 waves); wave w covers
// cols col0 = by*128 + w*64 (one head). A staged f32 -> hi/lo bf16 via LDS;
// B frags direct from global (L2-resident). 24 MFMA/wave/k-step.
// Epilogue: f16 h write + fused a_s/a_d scores (quad shfl reduction).
__global__ __launch_bounds__(128) void gemm_mfma_split(
    const float* __restrict__ A, const short* __restrict__ Wt_hi,
    const short* __restrict__ Wt_lo, __half* __restrict__ h16,
    const float* __restrict__ att_s, const float* __restrict__ att_d,
    float* __restrict__ a_s, float* __restrict__ a_d, int M, int K) {
  __shared__ alignas(16) short As_hi[32 * 32];
  __shared__ alignas(16) short As_lo[32 * 32];
  const int t = threadIdx.x;
  const int wave = t >> 6;
  const int lane = t & 63;
  const int quad = lane >> 4;
  const int m16 = lane & 15;
  const int row0 = blockIdx.x * 32;
  const int col0 = blockIdx.y * 128 + wave * 64;   // == head*64
  const int head = col0 >> 6;

  f32x4 acc[2][4] = {};  // [mt][nt]

  for (int k0 = 0; k0 < K; k0 += 32) {
    if (k0) __syncthreads();
    // ---- stage A tile 32 rows x 32 k as hi/lo bf16 (1 unit per thread) ----
    {
      const int r = t >> 2, seg = t & 3;
      const int gr = row0 + r;
      float vv[8] = {0.f, 0.f, 0.f, 0.f, 0.f, 0.f, 0.f, 0.f};
      if (gr < M) {
        const float* ap = A + (size_t)gr * K + k0 + seg * 8;
        const float4 v0 = *(const float4*)ap;
        const float4 v1 = *(const float4*)(ap + 4);
        vv[0] = v0.x; vv[1] = v0.y; vv[2] = v0.z; vv[3] = v0.w;
        vv[4] = v1.x; vv[5] = v1.y; vv[6] = v1.z; vv[7] = v1.w;
      }
      bf16x8 h8, l8;
#pragma unroll
      for (int j = 0; j < 8; ++j) {
        const short hi = f32_to_bf16_rne(vv[j]);
        h8[j] = hi;
        l8[j] = f32_to_bf16_rne(vv[j] - bf16_bits_to_f32(hi));
      }
      *(bf16x8*)(As_hi + r * 32 + seg * 8) = h8;
      *(bf16x8*)(As_lo + r * 32 + seg * 8) = l8;
    }
    bf16x8 b_hi[4], b_lo[4];
#pragma unroll
    for (int nt = 0; nt < 4; ++nt) {
      const size_t off = (size_t)(col0 + nt * 16 + m16) * K + k0 + quad * 8;
      b_hi[nt] = *(const bf16x8*)(Wt_hi + off);
      b_lo[nt] = *(const bf16x8*)(Wt_lo + off);
    }
    __syncthreads();
    bf16x8 a_hi[2], a_lo[2];
#pragma unroll
    for (int mt = 0; mt < 2; ++mt) {
      const int off = (mt * 16 + m16) * 32 + quad * 8;
      a_hi[mt] = *(const bf16x8*)(As_hi + off);
      a_lo[mt] = *(const bf16x8*)(As_lo + off);
    }
#pragma unroll
    for (int mt = 0; mt < 2; ++mt)
#pragma unroll
      for (int nt = 0; nt < 4; ++nt) {
        acc[mt][nt] = __builtin_amdgcn_mfma_f32_16x16x32_bf16(
            a_hi[mt], b_hi[nt], acc[mt][nt], 0, 0, 0);
        acc[mt][nt] = __builtin_amdgcn_mfma_f32_16x16x32_bf16(
            a_hi[mt], b_lo[nt], acc[mt][nt], 0, 0, 0);
        acc[mt][nt] = __builtin_amdgcn_mfma_f32_16x16x32_bf16(
            a_lo[mt], b_hi[nt], acc[mt][nt], 0, 0, 0);
      }
  }
  float sa[4], da[4];
#pragma unroll
  for (int nt = 0; nt < 4; ++nt) {
    sa[nt] = att_s[col0 + nt * 16 + m16];
    da[nt] = att_d[col0 + nt * 16 + m16];
  }
#pragma unroll
  for (int mt = 0; mt < 2; ++mt)
#pragma unroll
    for (int r = 0; r < 4; ++r) {
      const int gr = row0 + mt * 16 + quad * 4 + r;
      float ps = acc[mt][0][r] * sa[0] + acc[mt][1][r] * sa[1] +
                 acc[mt][2][r] * sa[2] + acc[mt][3][r] * sa[3];
      float pd = acc[mt][0][r] * da[0] + acc[mt][1][r] * da[1] +
                 acc[mt][2][r] * da[2] + acc[mt][3][r] * da[3];
#pragma unroll
      for (int off = 1; off <= 8; off <<= 1) {
        ps += __shfl_xor(ps, off);
        pd += __shfl_xor(pd, off);
      }
      if (gr < M) {
        if (m16 == 0) {
          a_s[gr * HEADS + head] = ps;
          a_d[gr * HEADS + head] = pd;
        }
#pragma unroll
        for (int nt = 0; nt < 4; ++nt)
          h16[(size_t)gr * HC + col0 + nt * 16 + m16] =
              __float2half(acc[mt][nt][r]);
      }
    }
}

// ============ ELL build: one kernel, no histogram/scan needed ==============
__global__ __launch_bounds__(256) void ell_scatter_kernel(
    const int* __restrict__ src, const int* __restrict__ dst,
    int* __restrict__ cnt, int* __restrict__ ell, int E_raw, int Etot) {
  const int e = blockIdx.x * 256 + threadIdx.x;
  if (e >= Etot) return;
  const int s = (e < E_raw) ? src[e] : (e - E_raw);
  const int d = (e < E_raw) ? dst[e] : (e - E_raw);
  const int pos = atomicAdd(&cnt[d], 1);
  if (pos < ELLW) ell[d * ELLW + pos] = s;  // P(overflow) ~ 7e-18
}

// ================= fused softmax + aggregation (f16 gather) ================
// (verbatim r11) grid = N blocks. block b: head hd = b&3 (XCD-affine), nodes
// 4*(b>>2)..+3 (wave = node). lane: q = lane>>3 edge slot, oc = lane&7
// channel octet (16B load). fma_mix inner math.
// mode 0: out[n,c] = ELU(v + b[c]);  mode 1: out[n,c] = v.
__global__ __launch_bounds__(256) void gat_aggregate_kernel(
    const int* __restrict__ cnt, const int* __restrict__ ell,
    const __half* __restrict__ h16, const float* __restrict__ a_s,
    const float* __restrict__ a_d, const float* __restrict__ b,
    float* __restrict__ out, int mode) {
  const int bid = blockIdx.x;
  const int hd = bid & 3;
  const int n = (bid >> 2) * 4 + (threadIdx.x >> 6);
  const int lane = threadIdx.x & 63;
  const int q = lane >> 3;
  const int oc = lane & 7;
  const float ad = a_d[n * HEADS + hd];
  const int deg = cnt[n];
  const int* __restrict__ row = ell + n * ELLW;
  const char* hbase = (const char*)h16 + hd * 128 + oc * 16;  // bytes
  const float* asb = a_s + hd;
  float acc[8] = {0.f, 0.f, 0.f, 0.f, 0.f, 0.f, 0.f, 0.f};
  float den = 0.f;
  int i = q;
  for (; i + 8 < deg; i += 16) {
    const int s0 = row[i];
    const int s1 = row[i + 8];
    const float as0 = asb[s0 * 4];
    const float as1 = asb[s1 * 4];
    const uint4 u0 = *(const uint4*)(hbase + ((unsigned)s0 << 9));
    const uint4 u1 = *(const uint4*)(hbase + ((unsigned)s1 << 9));
    float a0 = as0 + ad; a0 = fmaxf(a0, 0.2f * a0);
    float a1 = as1 + ad; a1 = fmaxf(a1, 0.2f * a1);
    const float e0 = __expf(a0);
    const float e1 = __expf(a1);
    den += e0 + e1;
    fma_mix8(e0, u0, acc);
    fma_mix8(e1, u1, acc);
  }
  for (; i < deg; i += 8) {
    const int s = row[i];
    float a = asb[s * 4] + ad;
    a = fmaxf(a, 0.2f * a);
    const float ex = __expf(a);
    den += ex;
    const uint4 u = *(const uint4*)(hbase + ((unsigned)s << 9));
    fma_mix8(ex, u, acc);
  }
  // reduce across the 8 slots (lane bits 3,4,5)
#pragma unroll
  for (int off = 8; off <= 32; off <<= 1) {
#pragma unroll
    for (int k = 0; k < 8; ++k) acc[k] += __shfl_xor(acc[k], off);
    den += __shfl_xor(den, off);
  }
  if (lane < 8) {
    const float inv = 1.f / den;
    float u[8];
#pragma unroll
    for (int k = 0; k < 8; ++k) u[k] = acc[k] * inv;
    if (mode == 0) {
      const float* bb = b + hd * CDIM + oc * 8;
#pragma unroll
      for (int k = 0; k < 8; ++k) {
        const float t0 = u[k] + bb[k];
        u[k] = (t0 > 0.f) ? t0 : (__expf(t0) - 1.f);
      }
    }
    float* op = out + (size_t)n * HC + hd * CDIM + oc * 8;
    *(float4*)op = make_float4(u[0], u[1], u[2], u[3]);
    *(float4*)(op + 4) = make_float4(u[4], u[5], u[6], u[7]);
  }
}

// ---- fused output head: out[n,:] = (mean_h agg[n,h,:] + b2) @ Wout + bout --
// (verbatim r11) one wave per node; lane = channel c; shfl butterfly.
__global__ __launch_bounds__(256) void final_fused_kernel(
    const float* __restrict__ agg, const float* __restrict__ b2,
    const float* __restrict__ Wout, const float* __restrict__ bout,
    float* __restrict__ out, int N) {
  const int n = blockIdx.x * 4 + (threadIdx.x >> 6);
  const int c = threadIdx.x & 63;
  if (n >= N) return;
  const float* ar = agg + (size_t)n * HC;
  const float m = 0.25f * (ar[c] + ar[c + 64] + ar[c + 128] + ar[c + 192]) +
                  b2[c];
  const float4* wr = (const float4*)(Wout + c * 16);
  const float4 w0 = wr[0], w1 = wr[1], w2 = wr[2], w3 = wr[3];
  float p[16] = {m * w0.x, m * w0.y, m * w0.z, m * w0.w,
                 m * w1.x, m * w1.y, m * w1.z, m * w1.w,
                 m * w2.x, m * w2.y, m * w2.z, m * w2.w,
                 m * w3.x, m * w3.y, m * w3.z, m * w3.w};
#pragma unroll
  for (int off = 1; off < 64; off <<= 1)
#pragma unroll
    for (int j = 0; j < 16; ++j) p[j] += __shfl_xor(p[j], off);
  if (c == 0) {
    float* op = out + (size_t)n * 16;
    *(float4*)op = make_float4(p[0] + bout[0], p[1] + bout[1],
                               p[2] + bout[2], p[3] + bout[3]);
    *(float4*)(op + 4) = make_float4(p[4] + bout[4], p[5] + bout[5],
                                     p[6] + bout[6], p[7] + bout[7]);
    *(float4*)(op + 8) = make_float4(p[8] + bout[8], p[9] + bout[9],
                                     p[10] + bout[10], p[11] + bout[11]);
    *(float4*)(op + 12) = make_float4(p[12] + bout[12], p[13] + bout[13],
                                      p[14] + bout[14], p[15] + bout[15]);
  }
}

extern "C" void kernel_launch(void* const* d_in, const int* in_sizes, int n_in,
                              void* d_out, int out_size, void* d_ws, size_t ws_size,
                              hipStream_t stream) {
  const float* x      = (const float*)d_in[0];
  const int*   eidx   = (const int*)d_in[1];
  const float* W1     = (const float*)d_in[2];
  const float* att_s1 = (const float*)d_in[3];
  const float* att_d1 = (const float*)d_in[4];
  const float* b1     = (const float*)d_in[5];
  const float* W2     = (const float*)d_in[6];
  const float* att_s2 = (const float*)d_in[7];
  const float* att_d2 = (const float*)d_in[8];
  const float* b2     = (const float*)d_in[9];
  const float* Wout   = (const float*)d_in[10];
  const float* bout   = (const float*)d_in[11];
  float* out          = (float*)d_out;

  const int N     = in_sizes[0] / 128;   // 20000
  const int E_raw = in_sizes[1] / 2;     // 640000
  const int Etot  = E_raw + N;           // + self loops
  const int* src = eidx;
  const int* dst = eidx + E_raw;

  // ---- workspace layout (r11) ----
  float* ws = (float*)d_ws;
  float* buf_agg = ws;                          // [N,256] agg1/ELU out, agg2
  float* buf_as  = buf_agg + (size_t)N * HC;    // [N,4]
  float* buf_ad  = buf_as + (size_t)N * HEADS;  // [N,4]
  __half* h16    = (__half*)(buf_ad + (size_t)N * HEADS);  // [N,256] f16
  int* cnt  = (int*)(h16 + (size_t)N * HC);     // [N] degree counters
  int* ell  = cnt + N;                          // [N*ELLW]
  uintptr_t wp = ((uintptr_t)(ell + (size_t)N * ELLW) + 15) & ~(uintptr_t)15;
  short* wt1_hi = (short*)wp;                   // [256][128]
  short* wt1_lo = wt1_hi + 256 * 128;
  short* wt2_hi = wt1_lo + 256 * 128;           // [256][256]
  short* wt2_lo = wt2_hi + 256 * 256;

  const dim3 blk(256);
  const int g_edge = (Etot + 255) / 256;
  const dim3 g_gemm((N + 31) / 32, 2);          // 625 x 2 blocks (tile 32)
  const dim3 blk_gemm(128);

  // ================= weight pack + ELL build =================
  pack_w12_kernel<<<(384 * 256 + 255) / 256, blk, 0, stream>>>(
      W1, wt1_hi, wt1_lo, W2, wt2_hi, wt2_lo);
  hipMemsetAsync(cnt, 0, (size_t)N * sizeof(int), stream);
  ell_scatter_kernel<<<g_edge, blk, 0, stream>>>(src, dst, cnt, ell, E_raw, Etot);

  // ================= Layer 1 =================
  gemm_mfma_split<<<g_gemm, blk_gemm, 0, stream>>>(
      x, wt1_hi, wt1_lo, h16, att_s1, att_d1, buf_as, buf_ad, N, 128);
  gat_aggregate_kernel<<<N, blk, 0, stream>>>(cnt, ell, h16, buf_as,
                                              buf_ad, b1, buf_agg, 0);

  // ================= Layer 2 =================
  gemm_mfma_split<<<g_gemm, blk_gemm, 0, stream>>>(
      buf_agg, wt2_hi, wt2_lo, h16, att_s2, att_d2, buf_as, buf_ad, N, 256);
  gat_aggregate_kernel<<<N, blk, 0, stream>>>(cnt, ell, h16, buf_as,
                                              buf_ad, b2, buf_agg, 1);

  // ================= Output head (mean + bias + Wout fused) =================
  final_fused_kernel<<<(N + 3) / 4, blk, 0, stream>>>(buf_agg, b2, Wout, bout,
                                                      out, N);
}